// Round 12
// baseline (412.992 us; speedup 1.0000x reference)
//
#include <hip/hip_runtime.h>

typedef unsigned short u16;
typedef __attribute__((ext_vector_type(4))) float f32x4;
typedef __attribute__((ext_vector_type(8))) short bf16x8;

#define AS1 __attribute__((address_space(1)))
#define AS3 __attribute__((address_space(3)))

__device__ __forceinline__ float bf2f(u16 u) {
  union { unsigned int i; float f; } v; v.i = ((unsigned int)u) << 16; return v.f;
}
__device__ __forceinline__ u16 f2bf(float f) {
  union { float f; unsigned int i; } v; v.f = f;
  unsigned int r = v.i + 0x7fffu + ((v.i >> 16) & 1u);  // RNE
  return (u16)(r >> 16);
}
__device__ __forceinline__ void gload16(const void* g, void* l) {
  __builtin_amdgcn_global_load_lds((const AS1 unsigned int*)g, (AS3 unsigned int*)l, 16, 0, 0);
}

// device-scope generation barrier; all 256 blocks co-resident (72KB LDS -> <=2/CU)
__device__ __forceinline__ void gridbar(int* cnt, int* gen, int nblk) {
  __threadfence();
  __syncthreads();
  if (threadIdx.x == 0) {
    int g = __hip_atomic_load(gen, __ATOMIC_RELAXED, __HIP_MEMORY_SCOPE_AGENT);
    int arrived = __hip_atomic_fetch_add(cnt, 1, __ATOMIC_ACQ_REL, __HIP_MEMORY_SCOPE_AGENT);
    if (arrived == nblk - 1) {
      __hip_atomic_store(cnt, 0, __ATOMIC_RELAXED, __HIP_MEMORY_SCOPE_AGENT);
      __hip_atomic_fetch_add(gen, 1, __ATOMIC_ACQ_REL, __HIP_MEMORY_SCOPE_AGENT);
    } else {
      while (__hip_atomic_load(gen, __ATOMIC_ACQUIRE, __HIP_MEMORY_SCOPE_AGENT) == g)
        __builtin_amdgcn_s_sleep(2);
    }
  }
  __syncthreads();
}

constexpr int HB = (128 + 64) * 64;  // u16 per LDS buffer (24 KB); 3 buffers = 72 KB

// one 128x64 output tile, K=2048, 3-deep pipelined, T2-swizzled LDS
__device__ void run_tile(const u16* A, int lda, const u16* Bt, int ldb,
                         u16* D, u16* Dt, float* Df, int ldd, int lddt,
                         float scale, int m0, int n0, u16* lds) {
  constexpr int BM = 128, BN = 64, FM = 4, FN = 2, L = 6, NT = 32;
  const int lane = threadIdx.x & 63;
  const int w = threadIdx.x >> 6;
  const int wm = w >> 1, wn = w & 1;
  f32x4 acc[FM][FN];
  #pragma unroll
  for (int i = 0; i < FM; ++i)
    #pragma unroll
    for (int j = 0; j < FN; ++j)
      acc[i][j] = (f32x4){0.f, 0.f, 0.f, 0.f};
  const int srow = lane >> 3;
  const int scolz = (((lane & 7) << 3) ^ (srow << 3));
  const int rsw = (lane & 7) << 3;

  auto stagef = [&](int tt, int buf) {
    const int k0 = tt * 64;
    u16* base = &lds[buf * HB];
    #pragma unroll
    for (int c = w; c < BM / 8; c += 4)
      gload16(A + (size_t)(m0 + c * 8 + srow) * lda + k0 + scolz, base + c * 512);
    #pragma unroll
    for (int c = w; c < BN / 8; c += 4)
      gload16(Bt + (size_t)(n0 + c * 8 + srow) * ldb + k0 + scolz, base + BM * 64 + c * 512);
  };

  stagef(0, 0);
  stagef(1, 1);
  stagef(2, 2);
  __builtin_amdgcn_sched_barrier(0);
  asm volatile("s_waitcnt vmcnt(12)");
  __builtin_amdgcn_s_barrier();
  __builtin_amdgcn_sched_barrier(0);

  int cur = 0;
  for (int tt = 0; tt < NT; ++tt) {
    const u16* base = &lds[cur * HB];
    #pragma unroll
    for (int kk = 0; kk < 64; kk += 32) {
      const int cb = (kk + ((lane >> 4) << 3)) ^ rsw;
      bf16x8 af[FM], bfr[FN];
      #pragma unroll
      for (int i = 0; i < FM; ++i)
        af[i] = *(const bf16x8*)&base[(wm * (BM / 2) + i * 16 + (lane & 15)) * 64 + cb];
      #pragma unroll
      for (int j = 0; j < FN; ++j)
        bfr[j] = *(const bf16x8*)&base[BM * 64 + (wn * (BN / 2) + j * 16 + (lane & 15)) * 64 + cb];
      #pragma unroll
      for (int i = 0; i < FM; ++i)
        #pragma unroll
        for (int j = 0; j < FN; ++j)
          acc[i][j] = __builtin_amdgcn_mfma_f32_16x16x32_bf16(af[i], bfr[j], acc[i][j], 0, 0, 0);
    }
    if (tt + 1 < NT) {
      __builtin_amdgcn_s_barrier();
      __builtin_amdgcn_sched_barrier(0);
      if (tt + 3 < NT) {
        stagef(tt + 3, cur);
        __builtin_amdgcn_sched_barrier(0);
        asm volatile("s_waitcnt vmcnt(12)");
      } else if (tt + 2 < NT) {
        asm volatile("s_waitcnt vmcnt(6)");
      } else {
        asm volatile("s_waitcnt vmcnt(0)");
      }
      __builtin_amdgcn_s_barrier();
      __builtin_amdgcn_sched_barrier(0);
    }
    cur = (cur == 2) ? 0 : cur + 1;
  }
  // epilogue
  const int r4 = (lane >> 4) << 2;
  const int cc = lane & 15;
  #pragma unroll
  for (int i = 0; i < FM; ++i) {
    #pragma unroll
    for (int j = 0; j < FN; ++j) {
      const int row0 = m0 + wm * (BM / 2) + i * 16 + r4;
      const int col = n0 + wn * (BN / 2) + j * 16 + cc;
      float v[4];
      #pragma unroll
      for (int q = 0; q < 4; ++q) v[q] = acc[i][j][q] * scale;
      if (D) {
        #pragma unroll
        for (int q = 0; q < 4; ++q) D[(size_t)(row0 + q) * ldd + col] = f2bf(v[q]);
      }
      if (Df) {
        #pragma unroll
        for (int q = 0; q < 4; ++q) Df[(size_t)(row0 + q) * ldd + col] = v[q];
      }
      if (Dt) {
        ushort4 pk = make_ushort4(f2bf(v[0]), f2bf(v[1]), f2bf(v[2]), f2bf(v[3]));
        *(ushort4*)&Dt[(size_t)col * lddt + row0] = pk;
      }
    }
  }
}

struct MegaP {
  const float *Af, *AFf, *Cf, *BFf, *CFf, *DFf;
  u16 *Mb, *Nb, *KP, *Cb, *P1T, *P2T, *BFT, *E1T, *E2T, *E3T, *WB, *CFb;
  float* tv;
  float* out;   // B_hat f32 [2048][512]
  float* outD;  // D_hat f32 [512][512]
  int* bar;     // [0]=cnt [1]=gen
};

__global__ __launch_bounds__(256) void mega(MegaP P) {
  __shared__ __align__(16) u16 lds[3 * HB];
  const int b = blockIdx.x;
  const int tid = threadIdx.x;
  const int lr = tid >> 6, lc = tid & 63;
  const int w = tid >> 6, lane = tid & 63;

  // ---------- phase C: all input conversions (2176 units, stride 256) ----------
  {
    auto tile = reinterpret_cast<float(*)[65]>(lds);
    for (int u = b; u < 2176; u += 256) {
      __syncthreads();
      if (u < 1024) {              // Mb = A^T
        int tr = u >> 5, tc = u & 31;
        int r0 = tr << 6, c0 = tc << 6;
        #pragma unroll
        for (int p = 0; p < 16; ++p) {
          int r = p * 4 + lr;
          tile[r][lc] = P.Af[(size_t)(r0 + r) * 2048 + c0 + lc];
        }
        __syncthreads();
        #pragma unroll
        for (int p = 0; p < 16; ++p) {
          int r = p * 4 + lr;
          P.Mb[(size_t)(c0 + r) * 2048 + r0 + lc] = f2bf(tile[lc][r]);
        }
      } else if (u < 1536) {       // Nb = A_F straight
        const int n4 = (2048 * 2048) / 4;
        for (int i = (u - 1024) * 256 + tid; i < n4; i += 512 * 256) {
          float4 f = ((const float4*)P.AFf)[i];
          ((ushort4*)P.Nb)[i] = make_ushort4(f2bf(f.x), f2bf(f.y), f2bf(f.z), f2bf(f.w));
        }
      } else if (u < 1792) {       // Cb = C straight; KP cols0-511 = C^T
        int bb = u - 1536;
        int tr = bb >> 5, tc = bb & 31;
        int r0 = tr << 6, c0 = tc << 6;
        #pragma unroll
        for (int p = 0; p < 16; ++p) {
          int r = p * 4 + lr;
          float v = P.Cf[(size_t)(r0 + r) * 2048 + c0 + lc];
          tile[r][lc] = v;
          P.Cb[(size_t)(r0 + r) * 2048 + c0 + lc] = f2bf(v);
        }
        __syncthreads();
        #pragma unroll
        for (int p = 0; p < 16; ++p) {
          int r = p * 4 + lr;
          P.KP[(size_t)(c0 + r) * 2048 + r0 + lc] = f2bf(tile[lc][r]);
        }
      } else if (u < 2048) {       // BFT = B_F^T
        int bb = u - 1792;
        int tr = bb >> 3, tc = bb & 7;
        int r0 = tr << 6, c0 = tc << 6;
        #pragma unroll
        for (int p = 0; p < 16; ++p) {
          int r = p * 4 + lr;
          tile[r][lc] = P.BFf[(size_t)(r0 + r) * 512 + c0 + lc];
        }
        __syncthreads();
        #pragma unroll
        for (int p = 0; p < 16; ++p) {
          int r = p * 4 + lr;
          P.BFT[(size_t)(c0 + r) * 2048 + r0 + lc] = f2bf(tile[lc][r]);
        }
      } else {                     // CFb = C_F straight
        const int n4 = (512 * 2048) / 4;
        for (int i = (u - 2048) * 256 + tid; i < n4; i += 128 * 256) {
          float4 f = ((const float4*)P.CFf)[i];
          ((ushort4*)P.CFb)[i] = make_ushort4(f2bf(f.x), f2bf(f.y), f2bf(f.z), f2bf(f.w));
        }
      }
    }
  }
  gridbar(P.bar, P.bar + 1, 256);

  // ---------- phases 0..2: chain (256 tiles each: 128 P + 128 e) ----------
  {
    const int t = ((b & 7) << 5) + (b >> 3);  // swizzled 0..255
    const int tt = t & 127;
    const int m0 = (tt >> 3) * 128, n0 = (tt & 7) * 64;
    // phase 0: P1 = M@P0 | e1 = N@e0
    if (t < 128) run_tile(P.Mb, 2048, P.Cb, 2048, P.KP + 512, P.P1T, nullptr, 2048, 2048, 1.f, m0, n0, lds);
    else         run_tile(P.Nb, 2048, P.BFT, 2048, nullptr, P.E1T, nullptr, 0, 2048, 1.f, m0, n0, lds);
    gridbar(P.bar, P.bar + 1, 256);
    // phase 1: P2 = M@P1 | e2 = N@e1
    if (t < 128) run_tile(P.Mb, 2048, P.P1T, 2048, P.KP + 1024, P.P2T, nullptr, 2048, 2048, 1.f, m0, n0, lds);
    else         run_tile(P.Nb, 2048, P.E1T, 2048, nullptr, P.E2T, nullptr, 0, 2048, 1.f, m0, n0, lds);
    gridbar(P.bar, P.bar + 1, 256);
    // phase 2: P3 = M@P2 (D only) | e3 = N@e2
    if (t < 128) run_tile(P.Mb, 2048, P.P2T, 2048, P.KP + 1536, nullptr, nullptr, 2048, 0, 1.f, m0, n0, lds);
    else         run_tile(P.Nb, 2048, P.E2T, 2048, nullptr, P.E3T, nullptr, 0, 2048, 1.f, m0, n0, lds);
    gridbar(P.bar, P.bar + 1, 256);
  }

  // ---------- phase 3: blocks 0-127: w_k = C_F@e_k ; blocks 128-255: rowsum(KP) ----------
  if (b < 128) {
    const int t = ((b & 7) << 4) + (b >> 3);  // 0..127
    const int k = t >> 5;
    const int tt = t & 31;
    const int m0 = (tt >> 3) * 128, n0 = (tt & 7) * 64;
    const u16* eT = (k == 0) ? P.BFT : (k == 1) ? P.E1T : (k == 2) ? P.E2T : P.E3T;
    run_tile(P.CFb, 2048, eT, 2048, nullptr, P.WB + 512 * k, nullptr, 0, 2048, 1.f, m0, n0, lds);
  } else {
    // t[row] = sum_j KP[row][j]; 16 rows per block (4 per wave)
    #pragma unroll
    for (int rr = 0; rr < 4; ++rr) {
      int row = (b - 128) * 16 + w * 4 + rr;
      float s = 0.f;
      for (int k0 = lane * 8; k0 < 2048; k0 += 512) {
        bf16x8 mv = *(const bf16x8*)&P.KP[(size_t)row * 2048 + k0];
        #pragma unroll
        for (int e = 0; e < 8; ++e) s += bf2f((u16)mv[e]);
      }
      #pragma unroll
      for (int off = 32; off > 0; off >>= 1) s += __shfl_down(s, off);
      if (lane == 0) P.tv[row] = s;
    }
  }
  gridbar(P.bar, P.bar + 1, 256);

  // ---------- phase 4: blocks 0-127: B_hat = -(KP@WB^T) ; blocks 128-255: D_hat ----------
  if (b < 128) {
    const int t = ((b & 7) << 4) + (b >> 3);  // 0..127
    const int m0 = (t >> 3) * 128, n0 = (t & 7) * 64;
    run_tile(P.KP, 2048, P.WB, 2048, nullptr, nullptr, P.out, 512, 0, -1.f, m0, n0, lds);
  } else {
    float* ts = reinterpret_cast<float*>(lds);
    for (int i = tid; i < 2048; i += 256) ts[i] = P.tv[i];
    __syncthreads();
    int row = (b - 128) * 4 + w;
    float s = 0.f;
    for (int k0 = lane * 4; k0 < 2048; k0 += 256) {
      float4 c4 = *(const float4*)&P.Cf[(size_t)row * 2048 + k0];
      s += c4.x * ts[k0] + c4.y * ts[k0 + 1] + c4.z * ts[k0 + 2] + c4.w * ts[k0 + 3];
    }
    #pragma unroll
    for (int off = 32; off > 0; off >>= 1) s += __shfl_down(s, off);
    s = __shfl(s, 0);
    float coef = 0.5f * (1.0f - s) * (1.0f / 512.0f);
    int j = lane * 8;
    #pragma unroll
    for (int e = 0; e < 8; ++e)
      P.outD[(size_t)row * 512 + j + e] = coef + 0.5f * P.DFf[(size_t)row * 512 + j + e];
  }
}

extern "C" void kernel_launch(void* const* d_in, const int* in_sizes, int n_in,
                              void* d_out, int out_size, void* d_ws, size_t ws_size,
                              hipStream_t stream) {
  (void)in_sizes; (void)n_in; (void)out_size; (void)ws_size;
  const size_t NN = 2048ull * 2048ull;
  const size_t SK = 512ull * 2048ull;
  char* ws = (char*)d_ws;
  MegaP P;
  P.Cf  = (const float*)d_in[0];
  P.Af  = (const float*)d_in[1];
  P.AFf = (const float*)d_in[2];
  P.BFf = (const float*)d_in[3];
  P.CFf = (const float*)d_in[4];
  P.DFf = (const float*)d_in[5];
  P.Mb  = (u16*)ws;
  P.Nb  = P.Mb + NN;
  P.KP  = P.Nb + NN;
  P.Cb  = P.KP + NN;
  P.P1T = P.Cb + SK;
  P.P2T = P.P1T + SK;
  P.BFT = P.P2T + SK;
  P.E1T = P.BFT + SK;
  P.E2T = P.E1T + SK;
  P.E3T = P.E2T + SK;
  P.WB  = P.E3T + SK;
  P.CFb = P.WB + SK;
  P.tv  = (float*)(P.CFb + SK);
  P.bar = (int*)(ws + (100ull << 20));  // 100 MB offset, well past buffers (~46 MB)
  P.out  = (float*)d_out;
  P.outD = (float*)d_out + 2048 * 512;

  hipMemsetAsync(P.bar, 0, 256, stream);
  mega<<<256, 256, 0, stream>>>(P);
}

// Round 13
// 137.052 us; speedup vs baseline: 3.0134x; 3.0134x over previous
//
#include <hip/hip_runtime.h>

typedef unsigned short u16;
typedef __attribute__((ext_vector_type(4))) float f32x4;
typedef __attribute__((ext_vector_type(8))) short bf16x8;

#define AS1 __attribute__((address_space(1)))
#define AS3 __attribute__((address_space(3)))

__device__ __forceinline__ float bf2f(u16 u) {
  union { unsigned int i; float f; } v; v.i = ((unsigned int)u) << 16; return v.f;
}
__device__ __forceinline__ u16 f2bf(float f) {
  union { float f; unsigned int i; } v; v.f = f;
  unsigned int r = v.i + 0x7fffu + ((v.i >> 16) & 1u);  // RNE
  return (u16)(r >> 16);
}
__device__ __forceinline__ void gload16(const void* g, void* l) {
  __builtin_amdgcn_global_load_lds((const AS1 unsigned int*)g, (AS3 unsigned int*)l, 16, 0, 0);
}

struct GemmDesc {
  const u16* A;      // [M][K] bf16, row stride lda
  const u16* Bt;     // [N][K] bf16, row stride ldb (B transposed)
  u16* D;            // optional bf16 out, row stride ldd
  u16* Dt;           // optional bf16 transposed out [N][M], row stride lddt
  float* Df;         // optional f32 out, row stride ldd
  int M, N, K, lda, ldb, ldd, lddt, tn, tiles;
  float scale;
};
struct GemmBatch { GemmDesc d[4]; int nd; };

template<int BM, int BN, int FM, int FN>
__device__ __forceinline__ void epilogue(const GemmDesc& d, f32x4 (&acc)[FM][FN],
                                         int m0, int n0, int wm, int wn, int lane) {
  const int r4 = (lane >> 4) << 2;
  const int cc = lane & 15;
  #pragma unroll
  for (int i = 0; i < FM; ++i) {
    #pragma unroll
    for (int j = 0; j < FN; ++j) {
      const int row0 = m0 + wm * (BM / 2) + i * 16 + r4;
      const int col = n0 + wn * (BN / 2) + j * 16 + cc;
      float v[4];
      #pragma unroll
      for (int q = 0; q < 4; ++q) v[q] = acc[i][j][q];
      if (d.scale != 1.0f) {
        #pragma unroll
        for (int q = 0; q < 4; ++q) v[q] *= d.scale;
      }
      if (d.D) {
        #pragma unroll
        for (int q = 0; q < 4; ++q) d.D[(size_t)(row0 + q) * d.ldd + col] = f2bf(v[q]);
      }
      if (d.Df) {
        #pragma unroll
        for (int q = 0; q < 4; ++q) d.Df[(size_t)(row0 + q) * d.ldd + col] = v[q];
      }
      if (d.Dt) {
        ushort4 pk = make_ushort4(f2bf(v[0]), f2bf(v[1]), f2bf(v[2]), f2bf(v[3]));
        *(ushort4*)&d.Dt[(size_t)col * d.lddt + row0] = pk;
      }
    }
  }
}

// ---------- 5-deep pipelined kernel, T2 XOR-swizzled LDS ----------
// LDS[r][c] holds global[r][c ^ ((r&7)<<3)]; linear LDS dest (gload16), pre-
// swizzled global source col, swizzled read col. 5 buffers (120 KB) -> 4 tiles
// (96 KB/block) in flight: latency hiding for the 1-block/CU zero-TLP regime.
template<int BM, int BN>
__global__ __launch_bounds__(256) void gemm_db(GemmBatch b) {
  const int nwg = gridDim.x;  // multiple of 8
  int t = ((blockIdx.x & 7) * (nwg >> 3)) + (blockIdx.x >> 3);
  int di = 0;
  while (di + 1 < b.nd && t >= b.d[di].tiles) { t -= b.d[di].tiles; ++di; }
  const GemmDesc d = b.d[di];
  const int tm = t / d.tn, tnn = t - tm * d.tn;
  const int m0 = tm * BM, n0 = tnn * BN;
  const int lane = threadIdx.x & 63;
  const int w = threadIdx.x >> 6;
  const int wm = w >> 1, wn = w & 1;
  constexpr int FM = BM / 32, FN = BN / 32;
  constexpr int HB = (BM + BN) * 64;       // u16 elems per buffer
  __shared__ __align__(16) u16 lds[5 * HB];
  f32x4 acc[FM][FN];
  #pragma unroll
  for (int i = 0; i < FM; ++i)
    #pragma unroll
    for (int j = 0; j < FN; ++j)
      acc[i][j] = (f32x4){0.f, 0.f, 0.f, 0.f};
  const int srow = lane >> 3;
  const int scolz = (((lane & 7) << 3) ^ (srow << 3));  // pre-swizzled source col
  const int rsw = (lane & 7) << 3;                      // read-side XOR constant
  const int nt = d.K / 64;                              // >= 5 in all uses (K=2048)

  auto stagef = [&](int tt, int buf) {
    const int k0 = tt * 64;
    u16* base = &lds[buf * HB];
    #pragma unroll
    for (int c = w; c < BM / 8; c += 4)
      gload16(d.A + (size_t)(m0 + c * 8 + srow) * d.lda + k0 + scolz, base + c * 512);
    #pragma unroll
    for (int c = w; c < BN / 8; c += 4)
      gload16(d.Bt + (size_t)(n0 + c * 8 + srow) * d.ldb + k0 + scolz, base + BM * 64 + c * 512);
  };

  // prologue: 5-deep prefetch
  stagef(0, 0);
  stagef(1, 1);
  stagef(2, 2);
  stagef(3, 3);
  stagef(4, 4);
  __builtin_amdgcn_sched_barrier(0);
  asm volatile("s_waitcnt vmcnt(24)");   // tile0's 6 loads landed (ours)
  __builtin_amdgcn_s_barrier();          // everyone's tile0 landed
  __builtin_amdgcn_sched_barrier(0);

  int cur = 0;
  for (int tt = 0; tt < nt; ++tt) {
    const u16* base = &lds[cur * HB];
    #pragma unroll
    for (int kk = 0; kk < 64; kk += 32) {
      const int cb = (kk + ((lane >> 4) << 3)) ^ rsw;  // swizzled col base
      bf16x8 af[FM], bfr[FN];
      #pragma unroll
      for (int i = 0; i < FM; ++i)
        af[i] = *(const bf16x8*)&base[(wm * (BM / 2) + i * 16 + (lane & 15)) * 64 + cb];
      #pragma unroll
      for (int j = 0; j < FN; ++j)
        bfr[j] = *(const bf16x8*)&base[BM * 64 + (wn * (BN / 2) + j * 16 + (lane & 15)) * 64 + cb];
      #pragma unroll
      for (int i = 0; i < FM; ++i)
        #pragma unroll
        for (int j = 0; j < FN; ++j)
          acc[i][j] = __builtin_amdgcn_mfma_f32_16x16x32_bf16(af[i], bfr[j], acc[i][j], 0, 0, 0);
    }
    if (tt + 1 < nt) {
      __builtin_amdgcn_s_barrier();      // all waves done reading buf[cur]
      __builtin_amdgcn_sched_barrier(0);
      if (tt + 5 < nt) {
        stagef(tt + 5, cur);             // refill freed buffer; loads fly across barrier
        __builtin_amdgcn_sched_barrier(0);
        asm volatile("s_waitcnt vmcnt(24)");   // tile tt+1 landed; 4 ahead in flight
      } else if (tt + 4 < nt) {
        asm volatile("s_waitcnt vmcnt(18)");
      } else if (tt + 3 < nt) {
        asm volatile("s_waitcnt vmcnt(12)");
      } else if (tt + 2 < nt) {
        asm volatile("s_waitcnt vmcnt(6)");
      } else {
        asm volatile("s_waitcnt vmcnt(0)");
      }
      __builtin_amdgcn_s_barrier();      // everyone's tile tt+1 landed
      __builtin_amdgcn_sched_barrier(0);
    }
    cur = (cur == 4) ? 0 : cur + 1;
  }
  epilogue<BM, BN, FM, FN>(d, acc, m0, n0, wm, wn, lane);
}

// ---------- one fused conversion kernel: 2688 units, grid 1344 x2 ----------
__global__ __launch_bounds__(256) void conv_all(const float* Af, const float* AFf,
                                                const float* Cf, const float* BFf,
                                                const float* CFf,
                                                u16* Mb, u16* Nb, u16* NbT, u16* Cb,
                                                u16* KP, u16* BFT, u16* CFb) {
  __shared__ float tile[64][65];
  const int tid = threadIdx.x;
  const int lr = tid >> 6, lc = tid & 63;
  for (int u = blockIdx.x; u < 2688; u += 1344) {
    __syncthreads();
    if (u < 1024) {              // Mb = A^T
      int tr = u >> 5, tc = u & 31;
      int r0 = tr << 6, c0 = tc << 6;
      #pragma unroll
      for (int p = 0; p < 16; ++p) {
        int r = p * 4 + lr;
        tile[r][lc] = Af[(size_t)(r0 + r) * 2048 + c0 + lc];
      }
      __syncthreads();
      #pragma unroll
      for (int p = 0; p < 16; ++p) {
        int r = p * 4 + lr;
        Mb[(size_t)(c0 + r) * 2048 + r0 + lc] = f2bf(tile[lc][r]);
      }
    } else if (u < 2048) {       // Nb = A_F straight ; NbT = A_F^T
      int bb = u - 1024;
      int tr = bb >> 5, tc = bb & 31;
      int r0 = tr << 6, c0 = tc << 6;
      #pragma unroll
      for (int p = 0; p < 16; ++p) {
        int r = p * 4 + lr;
        float v = AFf[(size_t)(r0 + r) * 2048 + c0 + lc];
        tile[r][lc] = v;
        Nb[(size_t)(r0 + r) * 2048 + c0 + lc] = f2bf(v);
      }
      __syncthreads();
      #pragma unroll
      for (int p = 0; p < 16; ++p) {
        int r = p * 4 + lr;
        NbT[(size_t)(c0 + r) * 2048 + r0 + lc] = f2bf(tile[lc][r]);
      }
    } else if (u < 2304) {       // Cb = C straight ; KP cols 0-511 = C^T
      int bb = u - 2048;
      int tr = bb >> 5, tc = bb & 31;
      int r0 = tr << 6, c0 = tc << 6;
      #pragma unroll
      for (int p = 0; p < 16; ++p) {
        int r = p * 4 + lr;
        float v = Cf[(size_t)(r0 + r) * 2048 + c0 + lc];
        tile[r][lc] = v;
        Cb[(size_t)(r0 + r) * 2048 + c0 + lc] = f2bf(v);
      }
      __syncthreads();
      #pragma unroll
      for (int p = 0; p < 16; ++p) {
        int r = p * 4 + lr;
        KP[(size_t)(c0 + r) * 2048 + r0 + lc] = f2bf(tile[lc][r]);
      }
    } else if (u < 2560) {       // BFT = B_F^T
      int bb = u - 2304;
      int tr = bb >> 3, tc = bb & 7;
      int r0 = tr << 6, c0 = tc << 6;
      #pragma unroll
      for (int p = 0; p < 16; ++p) {
        int r = p * 4 + lr;
        tile[r][lc] = BFf[(size_t)(r0 + r) * 512 + c0 + lc];
      }
      __syncthreads();
      #pragma unroll
      for (int p = 0; p < 16; ++p) {
        int r = p * 4 + lr;
        BFT[(size_t)(c0 + r) * 2048 + r0 + lc] = f2bf(tile[lc][r]);
      }
    } else {                     // CFb = C_F straight (128 stride-units)
      const int n4 = (512 * 2048) / 4;
      for (int i = (u - 2560) * 256 + tid; i < n4; i += 128 * 256) {
        float4 f = ((const float4*)CFf)[i];
        ((ushort4*)CFb)[i] = make_ushort4(f2bf(f.x), f2bf(f.y), f2bf(f.z), f2bf(f.w));
      }
    }
  }
}

// t[row] = sum_j KP[row][j], KP bf16 [n][width]; grid = n/4 blocks
__global__ __launch_bounds__(256) void rowsum_bf(const u16* KP, float* t, int width) {
  int w = threadIdx.x >> 6, lane = threadIdx.x & 63;
  int row = blockIdx.x * 4 + w;
  float s = 0.f;
  for (int k0 = lane * 8; k0 < width; k0 += 512) {
    bf16x8 mv = *(const bf16x8*)&KP[(size_t)row * width + k0];
    #pragma unroll
    for (int e = 0; e < 8; ++e) s += bf2f((u16)mv[e]);
  }
  #pragma unroll
  for (int off = 32; off > 0; off >>= 1) s += __shfl_down(s, off);
  if (lane == 0) t[row] = s;
}

// fused: u[row] = dot(C_row, t); D_hat[row][:] = 0.5*(1-u)/512 + 0.5*DF[row][:]
__global__ __launch_bounds__(256) void matvec_dhat(const float* Cm, const float* t,
                                                   const float* DF, float* out) {
  __shared__ float ts[2048];
  for (int i = threadIdx.x; i < 2048; i += 256) ts[i] = t[i];
  __syncthreads();
  int w = threadIdx.x >> 6, lane = threadIdx.x & 63;
  int row = blockIdx.x * 4 + w;
  float s = 0.f;
  for (int k0 = lane * 4; k0 < 2048; k0 += 256) {
    float4 c4 = *(const float4*)&Cm[(size_t)row * 2048 + k0];
    s += c4.x * ts[k0] + c4.y * ts[k0 + 1] + c4.z * ts[k0 + 2] + c4.w * ts[k0 + 3];
  }
  #pragma unroll
  for (int off = 32; off > 0; off >>= 1) s += __shfl_down(s, off);
  s = __shfl(s, 0);
  float coef = 0.5f * (1.0f - s) * (1.0f / 512.0f);
  int j = lane * 8;
  #pragma unroll
  for (int e = 0; e < 8; ++e)
    out[(size_t)row * 512 + j + e] = coef + 0.5f * DF[(size_t)row * 512 + j + e];
}

extern "C" void kernel_launch(void* const* d_in, const int* in_sizes, int n_in,
                              void* d_out, int out_size, void* d_ws, size_t ws_size,
                              hipStream_t stream) {
  (void)in_sizes; (void)n_in; (void)out_size; (void)ws_size;
  const float* Cf  = (const float*)d_in[0];  // [512][2048]
  const float* Af  = (const float*)d_in[1];  // [2048][2048]
  const float* AFf = (const float*)d_in[2];  // [2048][2048]
  const float* BFf = (const float*)d_in[3];  // [2048][512]
  const float* CFf = (const float*)d_in[4];  // [512][2048]
  const float* DFf = (const float*)d_in[5];  // [512][512]
  float* out = (float*)d_out;                // B_hat [2048][512] ++ D_hat [512][512]

  const size_t NN = 2048ull * 2048ull;
  const size_t SK = 512ull * 2048ull;
  char* ws = (char*)d_ws;
  u16* Mb   = (u16*)ws;            // M = A^T [2048][2048]
  u16* Nb   = Mb + NN;             // N = A_F [2048][2048]
  u16* NbT  = Nb + NN;             // N^T [2048][2048]
  u16* KP   = NbT + NN;            // [P0|P1|P2|P3] [2048][2048]
  u16* Cb   = KP + NN;             // C [512][2048] (= P0^T)
  u16* P1T  = Cb + SK;             // P1^T
  u16* P2T  = P1T + SK;            // P2^T
  u16* BFT  = P2T + SK;            // B_F^T = e0^T
  u16* E1T  = BFT + SK;            // e1^T
  u16* E2T  = E1T + SK;            // e2^T
  u16* R1   = E2T + SK;            // r1 = C_F N  [512][2048] straight
  u16* WB   = R1 + SK;             // [w0^T|w1^T|w2^T|w3^T] [512][2048]
  u16* CFb  = WB + SK;             // C_F [512][2048]
  float* tv = (float*)(CFb + SK);  // t [2048]

  auto mk = [](const u16* A, int lda, const u16* Bt, int ldb,
               u16* D, u16* Dt, float* Df, int ldd, int lddt,
               int M, int N, int K, float scale, int bm, int bn) {
    GemmDesc g; g.A = A; g.Bt = Bt; g.D = D; g.Dt = Dt; g.Df = Df;
    g.M = M; g.N = N; g.K = K; g.lda = lda; g.ldb = ldb; g.ldd = ldd; g.lddt = lddt;
    g.tn = N / bn; g.tiles = (M / bm) * (N / bn); g.scale = scale; return g;
  };

  // ---- all conversions in one launch ----
  conv_all<<<1344, 256, 0, stream>>>(Af, AFf, Cf, BFf, CFf, Mb, Nb, NbT, Cb, KP, BFT, CFb);

  // ---- G1 (256): P1 = M@P0 (D->KP+512, Dt->P1T) | e1 = N@e0 (Dt->E1T) ----
  { GemmBatch gb{}; gb.nd = 2;
    gb.d[0] = mk(Mb, 2048, Cb, 2048, KP + 512, P1T, nullptr, 2048, 2048, 2048, 512, 2048, 1.f, 128, 64);
    gb.d[1] = mk(Nb, 2048, BFT, 2048, nullptr, E1T, nullptr, 0, 2048, 2048, 512, 2048, 1.f, 128, 64);
    gemm_db<128, 64><<<256, 256, 0, stream>>>(gb); }

  // ---- G2 (256): P2 = M@P1 (D->KP+1024, Dt->P2T) | r1 = C_F@N (D->R1 straight) ----
  { GemmBatch gb{}; gb.nd = 2;
    gb.d[0] = mk(Mb, 2048, P1T, 2048, KP + 1024, P2T, nullptr, 2048, 2048, 2048, 512, 2048, 1.f, 128, 64);
    gb.d[1] = mk(CFb, 2048, NbT, 2048, R1, nullptr, nullptr, 2048, 0, 512, 2048, 2048, 1.f, 128, 64);
    gemm_db<128, 64><<<256, 256, 0, stream>>>(gb); }

  // ---- G3 (256): P3 = M@P2 (D->KP+1536) | e2 = N@e1 (Dt->E2T) ----
  { GemmBatch gb{}; gb.nd = 2;
    gb.d[0] = mk(Mb, 2048, P2T, 2048, KP + 1536, nullptr, nullptr, 2048, 0, 2048, 512, 2048, 1.f, 128, 64);
    gb.d[1] = mk(Nb, 2048, E1T, 2048, nullptr, E2T, nullptr, 0, 2048, 2048, 512, 2048, 1.f, 128, 64);
    gemm_db<128, 64><<<256, 256, 0, stream>>>(gb); }

  // ---- G4 (128): w0 = C_F@e0 | w1 = C_F@e1 | w2 = r1@e1 | w3 = r1@e2 (Dt->WB+512k) ----
  { GemmBatch gb{}; gb.nd = 4;
    gb.d[0] = mk(CFb, 2048, BFT, 2048, nullptr, WB, nullptr, 0, 2048, 512, 512, 2048, 1.f, 128, 64);
    gb.d[1] = mk(CFb, 2048, E1T, 2048, nullptr, WB + 512, nullptr, 0, 2048, 512, 512, 2048, 1.f, 128, 64);
    gb.d[2] = mk(R1, 2048, E1T, 2048, nullptr, WB + 1024, nullptr, 0, 2048, 512, 512, 2048, 1.f, 128, 64);
    gb.d[3] = mk(R1, 2048, E2T, 2048, nullptr, WB + 1536, nullptr, 0, 2048, 512, 512, 2048, 1.f, 128, 64);
    gemm_db<128, 64><<<128, 256, 0, stream>>>(gb); }

  // ---- G5 (128): B_hat = -(KP @ WB^T) -> d_out f32, K=2048 ----
  { GemmBatch gb{}; gb.nd = 1;
    gb.d[0] = mk(KP, 2048, WB, 2048, nullptr, nullptr, out, 512, 0, 2048, 512, 2048, -1.f, 128, 64);
    gemm_db<128, 64><<<128, 256, 0, stream>>>(gb); }

  // ---- D_hat: t = rowsum(KP) ; u = C t ; D_hat fused ----
  rowsum_bf<<<512, 256, 0, stream>>>(KP, tv, 2048);
  matvec_dhat<<<128, 256, 0, stream>>>(Cf, tv, DFf, out + 2048 * 512);
}